// Round 6
// baseline (747.422 us; speedup 1.0000x reference)
//
#include <hip/hip_runtime.h>
#include <hip/hip_fp16.h>

// Masked Sinkhorn via diagonal-scaling algebra on A = s+EPS:
//   c <- 1/(A^T r), r <- 1/(A c), out = A ∘ (r9 c8^T) on valid block.
// R6: fp16 compressed A (q) with EPS baked in and zeros beyond nc;
// separate tiny c-reduce dispatches (R5's folded reduce cost 64MB/pass of
// redundant partial reads); 8-row batched inner loops (independent loads,
// 8-way-ILP packed butterfly) to remove per-row latency chains.
// Chain: c0 -> r1 -> c2 -> r3 -> c4 -> r5 -> c6 -> r7 -> c8 -> r9 -> out.

namespace {
constexpr int B_ = 64;
constexpr int N_ = 1024;
constexpr int M_ = 1024;
constexpr float EPS_ = 1e-4f;
constexpr int PCHUNK = 16;        // row chunks for column-sum partials
constexpr int RPC = N_ / PCHUNK;  // 64 rows per block-chunk
}

typedef float f32x4_ __attribute__((ext_vector_type(4)));

__device__ __forceinline__ float4 nt_load4(const float* p) {
    f32x4_ v = __builtin_nontemporal_load(reinterpret_cast<const f32x4_*>(p));
    return float4{v.x, v.y, v.z, v.w};
}
__device__ __forceinline__ void nt_store4(float* p, float a, float b, float c, float d) {
    f32x4_ v = {a, b, c, d};
    __builtin_nontemporal_store(v, reinterpret_cast<f32x4_*>(p));
}
__device__ __forceinline__ void dq8(const uint4& r, float* f) {
    float2 x;
    x = __half22float2(*reinterpret_cast<const __half2*>(&r.x)); f[0] = x.x; f[1] = x.y;
    x = __half22float2(*reinterpret_cast<const __half2*>(&r.y)); f[2] = x.x; f[3] = x.y;
    x = __half22float2(*reinterpret_cast<const __half2*>(&r.z)); f[4] = x.x; f[5] = x.y;
    x = __half22float2(*reinterpret_cast<const __half2*>(&r.w)); f[6] = x.x; f[7] = x.y;
}

// ---------------------------------------------------------------------------
// Prep: q = fp16(s+EPS) for valid rows (0 beyond nc), + iter-0 column partials.
// grid (PCHUNK, B), block 256 = 4 waves x 16 rows. Lane owns 8 cols per 512-tile.
__global__ void prep_pass(const float* __restrict__ s,
                          __half* __restrict__ q,
                          float* __restrict__ partial,
                          const int* __restrict__ nrows,
                          const int* __restrict__ ncols) {
    __shared__ float lds[4][M_];
    const int b = blockIdx.y, p = blockIdx.x;
    const int nr = nrows[b], nc = ncols[b];
    const int wave = threadIdx.x >> 6, lane = threadIdx.x & 63;

    float ca[16];
#pragma unroll
    for (int k = 0; k < 16; ++k) ca[k] = 0.f;

    const int rbeg = p * RPC + wave * 16;
    const int rend = min(rbeg + 16, nr);
    const float* sb = s + (size_t)b * N_ * M_;
    __half* qb = q + (size_t)b * N_ * M_;

    for (int n = rbeg; n < rend; ++n) {
#pragma unroll
        for (int t = 0; t < 2; ++t) {
            const int m0 = t * 512 + lane * 8;
            const float4 v0 = nt_load4(sb + (size_t)n * M_ + m0);
            const float4 v1 = nt_load4(sb + (size_t)n * M_ + m0 + 4);
            float f[8] = {v0.x, v0.y, v0.z, v0.w, v1.x, v1.y, v1.z, v1.w};
#pragma unroll
            for (int j = 0; j < 8; ++j) {
                f[j] = (m0 + j < nc) ? f[j] + EPS_ : 0.f;  // t=0 always valid (nc>=512)
                ca[t * 8 + j] += f[j];
            }
            __half2 h0 = __floats2half2_rn(f[0], f[1]);
            __half2 h1 = __floats2half2_rn(f[2], f[3]);
            __half2 h2 = __floats2half2_rn(f[4], f[5]);
            __half2 h3 = __floats2half2_rn(f[6], f[7]);
            uint4 st;
            st.x = *reinterpret_cast<const unsigned*>(&h0);
            st.y = *reinterpret_cast<const unsigned*>(&h1);
            st.z = *reinterpret_cast<const unsigned*>(&h2);
            st.w = *reinterpret_cast<const unsigned*>(&h3);
            *reinterpret_cast<uint4*>(qb + (size_t)n * M_ + m0) = st;
        }
    }
#pragma unroll
    for (int t = 0; t < 2; ++t) {
        *reinterpret_cast<float4*>(&lds[wave][t * 512 + lane * 8]) =
            float4{ca[t * 8 + 0], ca[t * 8 + 1], ca[t * 8 + 2], ca[t * 8 + 3]};
        *reinterpret_cast<float4*>(&lds[wave][t * 512 + lane * 8 + 4]) =
            float4{ca[t * 8 + 4], ca[t * 8 + 5], ca[t * 8 + 6], ca[t * 8 + 7]};
    }
    __syncthreads();
    const int m0 = threadIdx.x * 4;
    const float4 a0 = *reinterpret_cast<const float4*>(&lds[0][m0]);
    const float4 a1 = *reinterpret_cast<const float4*>(&lds[1][m0]);
    const float4 a2 = *reinterpret_cast<const float4*>(&lds[2][m0]);
    const float4 a3 = *reinterpret_cast<const float4*>(&lds[3][m0]);
    float4 o;
    o.x = a0.x + a1.x + a2.x + a3.x;
    o.y = a0.y + a1.y + a2.y + a3.y;
    o.z = a0.z + a1.z + a2.z + a3.z;
    o.w = a0.w + a1.w + a2.w + a3.w;
    *reinterpret_cast<float4*>(partial + ((size_t)b * PCHUNK + p) * M_ + m0) = o;
}

// ---------------------------------------------------------------------------
// Reduce PCHUNK partials -> c[m] = 1/colsum. grid (M/256, B), block 256.
__global__ void reduce_colsum(const float* __restrict__ partial,
                              float* __restrict__ c) {
    const int b = blockIdx.y;
    const int m = blockIdx.x * 256 + threadIdx.x;
    const float* p = partial + (size_t)b * PCHUNK * M_ + m;
    float s = 0.f;
#pragma unroll
    for (int i = 0; i < PCHUNK; ++i) s += p[(size_t)i * M_];
    c[b * M_ + m] = (s == 0.f) ? 1.f : 1.f / s;  // s==0 only for cols >= nc
}

// ---------------------------------------------------------------------------
// Fused pair: r = 1/(q c) per row, column partials of q^T r. 8-row batches.
// grid (PCHUNK, B), block 256 = 4 waves x 16 rows.
__global__ void fused_pass(const __half* __restrict__ q,
                           const float* __restrict__ c,
                           float* __restrict__ partial,
                           const int* __restrict__ nrows,
                           const int* __restrict__ ncols) {
    __shared__ float lds[4][M_];
    const int b = blockIdx.y, p = blockIdx.x;
    const int nr = nrows[b];
    const int wave = threadIdx.x >> 6, lane = threadIdx.x & 63;

    // Lane's 16 c values. No masking needed: q is 0 beyond nc / rows >= nr
    // are predicated, so invalid-col terms vanish via q's zeros.
    const float* cb = c + b * M_;
    float cm[16];
#pragma unroll
    for (int t = 0; t < 2; ++t) {
        const float4 c0 = *reinterpret_cast<const float4*>(cb + t * 512 + lane * 8);
        const float4 c1 = *reinterpret_cast<const float4*>(cb + t * 512 + lane * 8 + 4);
        cm[t * 8 + 0] = c0.x; cm[t * 8 + 1] = c0.y; cm[t * 8 + 2] = c0.z; cm[t * 8 + 3] = c0.w;
        cm[t * 8 + 4] = c1.x; cm[t * 8 + 5] = c1.y; cm[t * 8 + 6] = c1.z; cm[t * 8 + 7] = c1.w;
    }

    float ca[16];
#pragma unroll
    for (int k = 0; k < 16; ++k) ca[k] = 0.f;

    const __half* qb = q + (size_t)b * N_ * M_;
    const int rbeg = p * RPC + wave * 16;

#pragma unroll
    for (int batch = 0; batch < 2; ++batch) {
        const int n0 = rbeg + batch * 8;
        uint4 raw[8][2];
#pragma unroll
        for (int rr = 0; rr < 8; ++rr) {
            const int n = n0 + rr;
            if (n < nr) {
                raw[rr][0] = *reinterpret_cast<const uint4*>(qb + (size_t)n * M_ + lane * 8);
                raw[rr][1] = *reinterpret_cast<const uint4*>(qb + (size_t)n * M_ + 512 + lane * 8);
            } else {
                raw[rr][0] = uint4{0u, 0u, 0u, 0u};
                raw[rr][1] = uint4{0u, 0u, 0u, 0u};
            }
        }
        float pr[8];
#pragma unroll
        for (int rr = 0; rr < 8; ++rr) {
            float f[16];
            dq8(raw[rr][0], f);
            dq8(raw[rr][1], f + 8);
            float a0 = 0.f, a1 = 0.f, a2 = 0.f, a3 = 0.f;
#pragma unroll
            for (int k = 0; k < 4; ++k) {
                a0 = fmaf(f[k], cm[k], a0);
                a1 = fmaf(f[4 + k], cm[4 + k], a1);
                a2 = fmaf(f[8 + k], cm[8 + k], a2);
                a3 = fmaf(f[12 + k], cm[12 + k], a3);
            }
            pr[rr] = (a0 + a1) + (a2 + a3);
        }
        // packed butterfly reduce: 6 levels x 8 independent values
#pragma unroll
        for (int off = 1; off < 64; off <<= 1) {
#pragma unroll
            for (int rr = 0; rr < 8; ++rr) pr[rr] += __shfl_xor(pr[rr], off, 64);
        }
#pragma unroll
        for (int rr = 0; rr < 8; ++rr) {
            const int n = n0 + rr;
            const float rn = (n < nr) ? 1.f / pr[rr] : 0.f;
            float f[16];
            dq8(raw[rr][0], f);
            dq8(raw[rr][1], f + 8);
#pragma unroll
            for (int k = 0; k < 16; ++k) ca[k] = fmaf(f[k], rn, ca[k]);
        }
    }
#pragma unroll
    for (int t = 0; t < 2; ++t) {
        *reinterpret_cast<float4*>(&lds[wave][t * 512 + lane * 8]) =
            float4{ca[t * 8 + 0], ca[t * 8 + 1], ca[t * 8 + 2], ca[t * 8 + 3]};
        *reinterpret_cast<float4*>(&lds[wave][t * 512 + lane * 8 + 4]) =
            float4{ca[t * 8 + 4], ca[t * 8 + 5], ca[t * 8 + 6], ca[t * 8 + 7]};
    }
    __syncthreads();
    const int m0 = threadIdx.x * 4;
    const float4 a0 = *reinterpret_cast<const float4*>(&lds[0][m0]);
    const float4 a1 = *reinterpret_cast<const float4*>(&lds[1][m0]);
    const float4 a2 = *reinterpret_cast<const float4*>(&lds[2][m0]);
    const float4 a3 = *reinterpret_cast<const float4*>(&lds[3][m0]);
    float4 o;
    o.x = a0.x + a1.x + a2.x + a3.x;
    o.y = a0.y + a1.y + a2.y + a3.y;
    o.z = a0.z + a1.z + a2.z + a3.z;
    o.w = a0.w + a1.w + a2.w + a3.w;
    *reinterpret_cast<float4*>(partial + ((size_t)b * PCHUNK + p) * M_ + m0) = o;
}

// ---------------------------------------------------------------------------
// Final: r9 = 1/(q c8) inline, out = q * r9 * c8 (fp32 nontemporal stores).
// Invalid rows: raw=0 & rn=0 -> zeros. Invalid cols: q=0 -> zeros.
// grid (PCHUNK, B), block 256 = 4 waves x 16 rows, 8-row batches.
__global__ void final_pass(const __half* __restrict__ q,
                           const float* __restrict__ c,
                           float* __restrict__ out,
                           const int* __restrict__ nrows,
                           const int* __restrict__ ncols) {
    const int b = blockIdx.y, p = blockIdx.x;
    const int nr = nrows[b];
    const int wave = threadIdx.x >> 6, lane = threadIdx.x & 63;

    const float* cb = c + b * M_;
    float cm[16];
#pragma unroll
    for (int t = 0; t < 2; ++t) {
        const float4 c0 = *reinterpret_cast<const float4*>(cb + t * 512 + lane * 8);
        const float4 c1 = *reinterpret_cast<const float4*>(cb + t * 512 + lane * 8 + 4);
        cm[t * 8 + 0] = c0.x; cm[t * 8 + 1] = c0.y; cm[t * 8 + 2] = c0.z; cm[t * 8 + 3] = c0.w;
        cm[t * 8 + 4] = c1.x; cm[t * 8 + 5] = c1.y; cm[t * 8 + 6] = c1.z; cm[t * 8 + 7] = c1.w;
    }

    const __half* qb = q + (size_t)b * N_ * M_;
    float* ob = out + (size_t)b * N_ * M_;
    const int rbeg = p * RPC + wave * 16;

#pragma unroll
    for (int batch = 0; batch < 2; ++batch) {
        const int n0 = rbeg + batch * 8;
        uint4 raw[8][2];
#pragma unroll
        for (int rr = 0; rr < 8; ++rr) {
            const int n = n0 + rr;
            if (n < nr) {
                raw[rr][0] = *reinterpret_cast<const uint4*>(qb + (size_t)n * M_ + lane * 8);
                raw[rr][1] = *reinterpret_cast<const uint4*>(qb + (size_t)n * M_ + 512 + lane * 8);
            } else {
                raw[rr][0] = uint4{0u, 0u, 0u, 0u};
                raw[rr][1] = uint4{0u, 0u, 0u, 0u};
            }
        }
        float pr[8];
#pragma unroll
        for (int rr = 0; rr < 8; ++rr) {
            float f[16];
            dq8(raw[rr][0], f);
            dq8(raw[rr][1], f + 8);
            float a0 = 0.f, a1 = 0.f, a2 = 0.f, a3 = 0.f;
#pragma unroll
            for (int k = 0; k < 4; ++k) {
                a0 = fmaf(f[k], cm[k], a0);
                a1 = fmaf(f[4 + k], cm[4 + k], a1);
                a2 = fmaf(f[8 + k], cm[8 + k], a2);
                a3 = fmaf(f[12 + k], cm[12 + k], a3);
            }
            pr[rr] = (a0 + a1) + (a2 + a3);
        }
#pragma unroll
        for (int off = 1; off < 64; off <<= 1) {
#pragma unroll
            for (int rr = 0; rr < 8; ++rr) pr[rr] += __shfl_xor(pr[rr], off, 64);
        }
#pragma unroll
        for (int rr = 0; rr < 8; ++rr) {
            const int n = n0 + rr;
            const float rn = (n < nr) ? 1.f / pr[rr] : 0.f;
            float f[16];
            dq8(raw[rr][0], f);
            dq8(raw[rr][1], f + 8);
#pragma unroll
            for (int t = 0; t < 2; ++t) {
                nt_store4(ob + (size_t)n * M_ + t * 512 + lane * 8,
                          f[t * 8 + 0] * rn * cm[t * 8 + 0],
                          f[t * 8 + 1] * rn * cm[t * 8 + 1],
                          f[t * 8 + 2] * rn * cm[t * 8 + 2],
                          f[t * 8 + 3] * rn * cm[t * 8 + 3]);
                nt_store4(ob + (size_t)n * M_ + t * 512 + lane * 8 + 4,
                          f[t * 8 + 4] * rn * cm[t * 8 + 4],
                          f[t * 8 + 5] * rn * cm[t * 8 + 5],
                          f[t * 8 + 6] * rn * cm[t * 8 + 6],
                          f[t * 8 + 7] * rn * cm[t * 8 + 7]);
            }
        }
    }
}

// ---------------------------------------------------------------------------
extern "C" void kernel_launch(void* const* d_in, const int* in_sizes, int n_in,
                              void* d_out, int out_size, void* d_ws, size_t ws_size,
                              hipStream_t stream) {
    const float* s = (const float*)d_in[0];
    const int* nrows = (const int*)d_in[1];
    const int* ncols = (const int*)d_in[2];
    float* out = (float*)d_out;

    const size_t qbytes = (size_t)B_ * N_ * M_ * sizeof(__half);  // 128 MiB
    __half* q = (__half*)d_ws;                                    // ws_size >= 136 MiB (proven R5)
    float* partial = (float*)((char*)d_ws + qbytes);              // B*PCHUNK*M floats (4 MiB)
    float* c = partial + (size_t)B_ * PCHUNK * M_;                // B*M floats (256 KiB)

    const dim3 blk(256);
    const dim3 g_chunk(PCHUNK, B_);
    const dim3 g_red(M_ / 256, B_);

    prep_pass<<<g_chunk, blk, 0, stream>>>(s, q, partial, nrows, ncols);
    reduce_colsum<<<g_red, blk, 0, stream>>>(partial, c);            // c0
    for (int k = 0; k < 4; ++k) {
        fused_pass<<<g_chunk, blk, 0, stream>>>(q, c, partial, nrows, ncols);
        reduce_colsum<<<g_red, blk, 0, stream>>>(partial, c);        // c2, c4, c6, c8
    }
    final_pass<<<g_chunk, blk, 0, stream>>>(q, c, out, nrows, ncols); // r9 + out
}

// Round 7
// 230.540 us; speedup vs baseline: 3.2420x; 3.2420x over previous
//
#include <hip/hip_runtime.h>
#include <hip/hip_fp16.h>

// Masked Sinkhorn via diagonal-scaling algebra on A = s+EPS:
//   c <- 1/(A^T r), r <- 1/(A c), out = A ∘ (r9 c8^T) on valid block.
// R7 = R5 structure (best measured: 277us) with ONE change: final stores are
// REGULAR float4 (R6 counters showed nontemporal stores caused 2.17x write
// amplification: WRITE_SIZE 583MB vs 268MB stored, 40% HBM eff).
// fp16 q (EPS baked in, zeros beyond nc) written once; 4 fused pair-passes
// (folded c-reduce, row-serial loop) + fused final. 6 dispatches.

namespace {
constexpr int B_ = 64;
constexpr int N_ = 1024;
constexpr int M_ = 1024;
constexpr float EPS_ = 1e-4f;
constexpr int PCHUNK = 16;        // row chunks for column-sum partials
constexpr int RPC = N_ / PCHUNK;  // 64 rows per chunk
}

typedef float f32x4_ __attribute__((ext_vector_type(4)));

__device__ __forceinline__ float4 nt_load4(const float* p) {
    f32x4_ v = __builtin_nontemporal_load(reinterpret_cast<const f32x4_*>(p));
    return float4{v.x, v.y, v.z, v.w};
}

// ---------------------------------------------------------------------------
// Prep: q = fp16(s+EPS) for valid rows (zeros for col-tiles beyond nc),
// plus iter-0 column-sum partials. grid (PCHUNK, B), block 256 = 4 waves x 16 rows.
__global__ void prep_pass(const float* __restrict__ s,
                          __half* __restrict__ q,
                          float* __restrict__ partial,
                          const int* __restrict__ nrows,
                          const int* __restrict__ ncols) {
    __shared__ float lds[4][M_];
    const int b = blockIdx.y, p = blockIdx.x;
    const int nr = nrows[b], nc = ncols[b];
    const int wave = threadIdx.x >> 6, lane = threadIdx.x & 63;

    float4 ca[4];
#pragma unroll
    for (int t = 0; t < 4; ++t) ca[t] = float4{0.f, 0.f, 0.f, 0.f};

    const int rbeg = p * RPC + wave * 16;
    const int rend = min(rbeg + 16, nr);
    const float* sb = s + (size_t)b * N_ * M_;
    __half* qb = q + (size_t)b * N_ * M_;

    for (int n = rbeg; n < rend; ++n) {
#pragma unroll
        for (int t = 0; t < 4; ++t) {
            const int m0 = t * 256 + lane * 4;
            float4 v = {0.f, 0.f, 0.f, 0.f};
            if (m0 < nc) {
                v = nt_load4(sb + (size_t)n * M_ + m0);
                v.x += EPS_; v.y += EPS_; v.z += EPS_; v.w += EPS_;
            }
            __half2 h01 = __floats2half2_rn(v.x, v.y);
            __half2 h23 = __floats2half2_rn(v.z, v.w);
            uint2 st;
            st.x = *reinterpret_cast<const unsigned*>(&h01);
            st.y = *reinterpret_cast<const unsigned*>(&h23);
            *reinterpret_cast<uint2*>(qb + (size_t)n * M_ + m0) = st;
            ca[t].x += v.x; ca[t].y += v.y; ca[t].z += v.z; ca[t].w += v.w;
        }
    }
#pragma unroll
    for (int t = 0; t < 4; ++t)
        *reinterpret_cast<float4*>(&lds[wave][t * 256 + lane * 4]) = ca[t];
    __syncthreads();
    const int m0 = threadIdx.x * 4;
    float4 a0 = *reinterpret_cast<const float4*>(&lds[0][m0]);
    float4 a1 = *reinterpret_cast<const float4*>(&lds[1][m0]);
    float4 a2 = *reinterpret_cast<const float4*>(&lds[2][m0]);
    float4 a3 = *reinterpret_cast<const float4*>(&lds[3][m0]);
    float4 o;
    o.x = a0.x + a1.x + a2.x + a3.x;
    o.y = a0.y + a1.y + a2.y + a3.y;
    o.z = a0.z + a1.z + a2.z + a3.z;
    o.w = a0.w + a1.w + a2.w + a3.w;
    *reinterpret_cast<float4*>(partial + ((size_t)b * PCHUNK + p) * M_ + m0) = o;
}

// ---------------------------------------------------------------------------
// Fused iteration pair: reduce partial_in -> c (in LDS, identical order in
// every block -> bitwise-consistent), then r = 1/(q c) per row and column
// partials of q^T r -> partial_out. grid (PCHUNK, B), block 256 = 4 waves x 16 rows.
// Lane owns cols {t*512 + lane*8 .. +7}, t=0,1.
__global__ void fused_pass_h(const __half* __restrict__ q,
                             const float* __restrict__ partial_in,
                             float* __restrict__ partial_out,
                             const int* __restrict__ nrows,
                             const int* __restrict__ ncols) {
    __shared__ float lds[4][M_];
    const int b = blockIdx.y, p = blockIdx.x;
    const int nr = nrows[b], nc = ncols[b];
    const int wave = threadIdx.x >> 6, lane = threadIdx.x & 63;

    // phase 1: c = 1/colsum into lds[0][.]
    {
        const int m0 = threadIdx.x * 4;
        const float* pp = partial_in + (size_t)b * PCHUNK * M_ + m0;
        float4 sacc = {0.f, 0.f, 0.f, 0.f};
#pragma unroll
        for (int i = 0; i < PCHUNK; ++i) {
            const float4 v = *reinterpret_cast<const float4*>(pp + (size_t)i * M_);
            sacc.x += v.x; sacc.y += v.y; sacc.z += v.z; sacc.w += v.w;
        }
        float4 cv;
        cv.x = (sacc.x == 0.f) ? 1.f : 1.f / sacc.x;
        cv.y = (sacc.y == 0.f) ? 1.f : 1.f / sacc.y;
        cv.z = (sacc.z == 0.f) ? 1.f : 1.f / sacc.z;
        cv.w = (sacc.w == 0.f) ? 1.f : 1.f / sacc.w;
        *reinterpret_cast<float4*>(&lds[0][m0]) = cv;
    }
    __syncthreads();

    // phase 2: lane's 16 c values, masked to 0 beyond nc
    float cm[16];
#pragma unroll
    for (int t = 0; t < 2; ++t)
#pragma unroll
        for (int j = 0; j < 8; ++j) {
            const int m = t * 512 + lane * 8 + j;
            const float v = lds[0][m];
            cm[t * 8 + j] = (m < nc) ? v : 0.f;
        }
    __syncthreads();  // lds reused for the column-partial combine below

    // phase 3: rows — dot -> r_n, accumulate q*r_n into column accumulators
    float ca[16];
#pragma unroll
    for (int k = 0; k < 16; ++k) ca[k] = 0.f;

    const int rbeg = p * RPC + wave * 16;
    const int rend = min(rbeg + 16, nr);
    const __half* qb = q + (size_t)b * N_ * M_;

    for (int n = rbeg; n < rend; ++n) {
        float f[16];
#pragma unroll
        for (int t = 0; t < 2; ++t) {
            const float4 raw = *reinterpret_cast<const float4*>(
                qb + (size_t)n * M_ + t * 512 + lane * 8);
            const __half2* hp = reinterpret_cast<const __half2*>(&raw);
#pragma unroll
            for (int k = 0; k < 4; ++k) {
                const float2 fr = __half22float2(hp[k]);
                f[t * 8 + 2 * k] = fr.x;
                f[t * 8 + 2 * k + 1] = fr.y;
            }
        }
        float acc = 0.f;
#pragma unroll
        for (int k = 0; k < 16; ++k) acc = fmaf(f[k], cm[k], acc);
#pragma unroll
        for (int off = 1; off < 64; off <<= 1)
            acc += __shfl_xor(acc, off, 64);
        const float rn = 1.f / acc;  // acc > 0 always (q,c > 0 on valid cols)
#pragma unroll
        for (int k = 0; k < 16; ++k) ca[k] = fmaf(f[k], rn, ca[k]);
    }

    // phase 4: combine 4 waves -> partial_out[b][p][:]
#pragma unroll
    for (int t = 0; t < 2; ++t) {
        float4 v0 = {ca[t * 8 + 0], ca[t * 8 + 1], ca[t * 8 + 2], ca[t * 8 + 3]};
        float4 v1 = {ca[t * 8 + 4], ca[t * 8 + 5], ca[t * 8 + 6], ca[t * 8 + 7]};
        *reinterpret_cast<float4*>(&lds[wave][t * 512 + lane * 8]) = v0;
        *reinterpret_cast<float4*>(&lds[wave][t * 512 + lane * 8 + 4]) = v1;
    }
    __syncthreads();
    const int m0 = threadIdx.x * 4;
    float4 a0 = *reinterpret_cast<const float4*>(&lds[0][m0]);
    float4 a1 = *reinterpret_cast<const float4*>(&lds[1][m0]);
    float4 a2 = *reinterpret_cast<const float4*>(&lds[2][m0]);
    float4 a3 = *reinterpret_cast<const float4*>(&lds[3][m0]);
    float4 o;
    o.x = a0.x + a1.x + a2.x + a3.x;
    o.y = a0.y + a1.y + a2.y + a3.y;
    o.z = a0.z + a1.z + a2.z + a3.z;
    o.w = a0.w + a1.w + a2.w + a3.w;
    *reinterpret_cast<float4*>(partial_out + ((size_t)b * PCHUNK + p) * M_ + m0) = o;
}

// ---------------------------------------------------------------------------
// Final: reduce partial_in -> c8, r9 = 1/(q c8) inline, out = q*r9*c8 in fp32
// with REGULAR float4 stores (the one change vs R5). Invalid rows/cols -> 0.
// grid (PCHUNK, B), block 256 = 4 waves x 16 rows.
__global__ void final_pass_h(const __half* __restrict__ q,
                             const float* __restrict__ partial_in,
                             float* __restrict__ out,
                             const int* __restrict__ nrows,
                             const int* __restrict__ ncols) {
    __shared__ float ldsc[M_];
    const int b = blockIdx.y, p = blockIdx.x;
    const int nr = nrows[b], nc = ncols[b];
    const int wave = threadIdx.x >> 6, lane = threadIdx.x & 63;

    {
        const int m0 = threadIdx.x * 4;
        const float* pp = partial_in + (size_t)b * PCHUNK * M_ + m0;
        float4 sacc = {0.f, 0.f, 0.f, 0.f};
#pragma unroll
        for (int i = 0; i < PCHUNK; ++i) {
            const float4 v = *reinterpret_cast<const float4*>(pp + (size_t)i * M_);
            sacc.x += v.x; sacc.y += v.y; sacc.z += v.z; sacc.w += v.w;
        }
        float4 cv;
        cv.x = (sacc.x == 0.f) ? 1.f : 1.f / sacc.x;
        cv.y = (sacc.y == 0.f) ? 1.f : 1.f / sacc.y;
        cv.z = (sacc.z == 0.f) ? 1.f : 1.f / sacc.z;
        cv.w = (sacc.w == 0.f) ? 1.f : 1.f / sacc.w;
        *reinterpret_cast<float4*>(&ldsc[m0]) = cv;
    }
    __syncthreads();

    float cm[16];
#pragma unroll
    for (int t = 0; t < 2; ++t)
#pragma unroll
        for (int j = 0; j < 8; ++j) {
            const int m = t * 512 + lane * 8 + j;
            const float v = ldsc[m];
            cm[t * 8 + j] = (m < nc) ? v : 0.f;
        }

    const int rbeg = p * RPC + wave * 16;
    const __half* qb = q + (size_t)b * N_ * M_;
    float* ob = out + (size_t)b * N_ * M_;

    for (int n = rbeg; n < rbeg + 16; ++n) {
        if (n >= nr) {  // zero row (wave-uniform branch)
            const float4 z = {0.f, 0.f, 0.f, 0.f};
#pragma unroll
            for (int t = 0; t < 2; ++t) {
                *reinterpret_cast<float4*>(ob + (size_t)n * M_ + t * 512 + lane * 8) = z;
                *reinterpret_cast<float4*>(ob + (size_t)n * M_ + t * 512 + lane * 8 + 4) = z;
            }
            continue;
        }
        float f[16];
#pragma unroll
        for (int t = 0; t < 2; ++t) {
            const float4 raw = *reinterpret_cast<const float4*>(
                qb + (size_t)n * M_ + t * 512 + lane * 8);
            const __half2* hp = reinterpret_cast<const __half2*>(&raw);
#pragma unroll
            for (int k = 0; k < 4; ++k) {
                const float2 fr = __half22float2(hp[k]);
                f[t * 8 + 2 * k] = fr.x;
                f[t * 8 + 2 * k + 1] = fr.y;
            }
        }
        float acc = 0.f;
#pragma unroll
        for (int k = 0; k < 16; ++k) acc = fmaf(f[k], cm[k], acc);
#pragma unroll
        for (int off = 1; off < 64; off <<= 1)
            acc += __shfl_xor(acc, off, 64);
        const float rn = 1.f / acc;
#pragma unroll
        for (int t = 0; t < 2; ++t) {
            float4 o0, o1;
            o0.x = f[t * 8 + 0] * rn * cm[t * 8 + 0];
            o0.y = f[t * 8 + 1] * rn * cm[t * 8 + 1];
            o0.z = f[t * 8 + 2] * rn * cm[t * 8 + 2];
            o0.w = f[t * 8 + 3] * rn * cm[t * 8 + 3];
            o1.x = f[t * 8 + 4] * rn * cm[t * 8 + 4];
            o1.y = f[t * 8 + 5] * rn * cm[t * 8 + 5];
            o1.z = f[t * 8 + 6] * rn * cm[t * 8 + 6];
            o1.w = f[t * 8 + 7] * rn * cm[t * 8 + 7];
            *reinterpret_cast<float4*>(ob + (size_t)n * M_ + t * 512 + lane * 8) = o0;
            *reinterpret_cast<float4*>(ob + (size_t)n * M_ + t * 512 + lane * 8 + 4) = o1;
        }
    }
}

// ---------------------------------------------------------------------------
extern "C" void kernel_launch(void* const* d_in, const int* in_sizes, int n_in,
                              void* d_out, int out_size, void* d_ws, size_t ws_size,
                              hipStream_t stream) {
    const float* s = (const float*)d_in[0];
    const int* nrows = (const int*)d_in[1];
    const int* ncols = (const int*)d_in[2];
    float* out = (float*)d_out;

    const size_t qbytes = (size_t)B_ * N_ * M_ * sizeof(__half);  // 128 MiB
    __half* q = (__half*)d_ws;                                    // ws proven >= 136 MiB (R5/R6 ran)
    float* pa = (float*)((char*)d_ws + qbytes);                   // B*PCHUNK*M floats (4 MiB)
    float* pb = pa + (size_t)B_ * PCHUNK * M_;                    // B*PCHUNK*M floats (4 MiB)

    const dim3 blk(256);
    const dim3 g_chunk(PCHUNK, B_);

    prep_pass<<<g_chunk, blk, 0, stream>>>(s, q, pa, nrows, ncols);
    fused_pass_h<<<g_chunk, blk, 0, stream>>>(q, pa, pb, nrows, ncols);  // c0 -> r1 -> p(c2)
    fused_pass_h<<<g_chunk, blk, 0, stream>>>(q, pb, pa, nrows, ncols);  // c2 -> r3 -> p(c4)
    fused_pass_h<<<g_chunk, blk, 0, stream>>>(q, pa, pb, nrows, ncols);  // c4 -> r5 -> p(c6)
    fused_pass_h<<<g_chunk, blk, 0, stream>>>(q, pb, pa, nrows, ncols);  // c6 -> r7 -> p(c8)
    final_pass_h<<<g_chunk, blk, 0, stream>>>(q, pa, out, nrows, ncols); // c8 -> r9 -> out
}